// Round 1
// baseline (815.828 us; speedup 1.0000x reference)
//
#include <hip/hip_runtime.h>

#define N_NODES 100000
#define N_EDGES 1600000
#define D_IN    128
#define D_OUT   32

// ---------------------------------------------------------------------------
// Kernel 1: h = relu(input @ W)   [N,128] @ [128,32] -> [N,32], fp32 vector.
// Block = 256 threads = 8 rows x 32 cols. W staged in LDS (16 KB).
// N_NODES % 8 == 0 so no tail guard needed (100000 / 8 = 12500 blocks).
// ---------------------------------------------------------------------------
__global__ __launch_bounds__(256) void gemm_relu_kernel(
    const float* __restrict__ input,
    const float* __restrict__ W,
    float* __restrict__ h)
{
    __shared__ float Ws[D_IN * D_OUT];
    for (int i = threadIdx.x; i < D_IN * D_OUT; i += 256) Ws[i] = W[i];
    __syncthreads();

    const int c = threadIdx.x & 31;
    const int r = blockIdx.x * 8 + (threadIdx.x >> 5);

    const float4* inrow = (const float4*)(input + (size_t)r * D_IN);
    float acc = 0.f;
#pragma unroll
    for (int k4 = 0; k4 < D_IN / 4; ++k4) {
        float4 v = inrow[k4];
        acc = fmaf(v.x, Ws[(k4 * 4 + 0) * D_OUT + c], acc);
        acc = fmaf(v.y, Ws[(k4 * 4 + 1) * D_OUT + c], acc);
        acc = fmaf(v.z, Ws[(k4 * 4 + 2) * D_OUT + c], acc);
        acc = fmaf(v.w, Ws[(k4 * 4 + 3) * D_OUT + c], acc);
    }
    h[(size_t)r * D_OUT + c] = fmaxf(acc, 0.f);
}

// ---------------------------------------------------------------------------
// Kernel 2: scatter  out[erow[e]] += dw1[etime[e]] * h[ecol[e]]
// 8 threads per edge, one float4 each -> gather coalesced within 8-lane group;
// 4 fp32 atomicAdds per thread (device-scope by default).
// ---------------------------------------------------------------------------
__global__ __launch_bounds__(256) void scatter_kernel(
    const float* __restrict__ h,
    const float* __restrict__ dw1,
    const int* __restrict__ erow,
    const int* __restrict__ ecol,
    const int* __restrict__ etime,
    float* __restrict__ out)
{
    const int idx = blockIdx.x * 256 + threadIdx.x;   // over N_EDGES * 8
    if (idx >= N_EDGES * 8) return;
    const int e = idx >> 3;
    const int q = idx & 7;

    const int   row = erow[e];
    const int   col = ecol[e];
    const float d   = dw1[etime[e]];

    const float4 v = ((const float4*)(h + (size_t)col * D_OUT))[q];
    float* o = out + (size_t)row * D_OUT + q * 4;
    atomicAdd(o + 0, d * v.x);
    atomicAdd(o + 1, d * v.y);
    atomicAdd(o + 2, d * v.z);
    atomicAdd(o + 3, d * v.w);
}

// ---------------------------------------------------------------------------
// Kernel 3: out[r,:] *= dw2[60*obs_t - arrive[r] - 1]
// ---------------------------------------------------------------------------
__global__ __launch_bounds__(256) void scale_kernel(
    float* __restrict__ out,
    const float* __restrict__ dw2,
    const int* __restrict__ arrive,
    const int* __restrict__ obs_t)
{
    const int idx = blockIdx.x * 256 + threadIdx.x;   // over N_NODES * 8
    if (idx >= N_NODES * 8) return;
    const int r = idx >> 3;
    const int q = idx & 7;

    const int   w = 60 * obs_t[0] - arrive[r] - 1;
    const float s = dw2[w];

    float4* p = (float4*)(out + (size_t)r * D_OUT) + q;
    float4 v = *p;
    v.x *= s; v.y *= s; v.z *= s; v.w *= s;
    *p = v;
}

extern "C" void kernel_launch(void* const* d_in, const int* in_sizes, int n_in,
                              void* d_out, int out_size, void* d_ws, size_t ws_size,
                              hipStream_t stream)
{
    const float* input  = (const float*)d_in[0];   // [N, 128]
    const float* W      = (const float*)d_in[1];   // [128, 32]
    const float* dw1    = (const float*)d_in[2];   // [3600, 1]
    const float* dw2    = (const float*)d_in[3];   // [3600, 1]
    const int*   erow   = (const int*)d_in[4];     // [E]
    const int*   ecol   = (const int*)d_in[5];     // [E]
    const int*   etime  = (const int*)d_in[6];     // [E]
    const int*   arrive = (const int*)d_in[7];     // [N]
    const int*   obs    = (const int*)d_in[8];     // scalar

    float* out = (float*)d_out;                    // [N, 32]
    float* h   = (float*)d_ws;                     // [N, 32] scratch (12.8 MB)

    // d_out is poisoned to 0xAA before every launch — zero it for the atomics.
    hipMemsetAsync(d_out, 0, (size_t)out_size * sizeof(float), stream);

    gemm_relu_kernel<<<N_NODES / 8, 256, 0, stream>>>(input, W, h);

    const int scatter_items = N_EDGES * 8;
    scatter_kernel<<<(scatter_items + 255) / 256, 256, 0, stream>>>(
        h, dw1, erow, ecol, etime, out);

    const int scale_items = N_NODES * 8;
    scale_kernel<<<(scale_items + 255) / 256, 256, 0, stream>>>(
        out, dw2, arrive, obs);
}

// Round 2
// 376.602 us; speedup vs baseline: 2.1663x; 2.1663x over previous
//
#include <hip/hip_runtime.h>

#define N_NODES 100000
#define N_EDGES 1600000
#define D_IN    128
#define D_OUT   32
#define SCAN_TILE 256
#define NTILES  ((N_NODES + SCAN_TILE - 1) / SCAN_TILE)   // 391

// ---------------------------------------------------------------------------
// Kernel 1: h = relu(input @ W)  (unchanged this round — next round's target)
// ---------------------------------------------------------------------------
__global__ __launch_bounds__(256) void gemm_relu_kernel(
    const float* __restrict__ input,
    const float* __restrict__ W,
    float* __restrict__ h)
{
    __shared__ float Ws[D_IN * D_OUT];
    for (int i = threadIdx.x; i < D_IN * D_OUT; i += 256) Ws[i] = W[i];
    __syncthreads();

    const int c = threadIdx.x & 31;
    const int r = blockIdx.x * 8 + (threadIdx.x >> 5);

    const float4* inrow = (const float4*)(input + (size_t)r * D_IN);
    float acc = 0.f;
#pragma unroll
    for (int k4 = 0; k4 < D_IN / 4; ++k4) {
        float4 v = inrow[k4];
        acc = fmaf(v.x, Ws[(k4 * 4 + 0) * D_OUT + c], acc);
        acc = fmaf(v.y, Ws[(k4 * 4 + 1) * D_OUT + c], acc);
        acc = fmaf(v.z, Ws[(k4 * 4 + 2) * D_OUT + c], acc);
        acc = fmaf(v.w, Ws[(k4 * 4 + 3) * D_OUT + c], acc);
    }
    h[(size_t)r * D_OUT + c] = fmaxf(acc, 0.f);
}

// ---------------------------------------------------------------------------
// Counting sort: histogram of edge rows
// ---------------------------------------------------------------------------
__global__ __launch_bounds__(256) void hist_kernel(
    const int* __restrict__ erow, int* __restrict__ cnt)
{
    const int e = blockIdx.x * 256 + threadIdx.x;
    if (e < N_EDGES) atomicAdd(&cnt[erow[e]], 1);
}

// Pass 1: per-256-tile inclusive scan; emit tile totals.
__global__ __launch_bounds__(256) void scan_p1_kernel(
    const int* __restrict__ cnt, int* __restrict__ tileinc, int* __restrict__ bsum)
{
    __shared__ int s[SCAN_TILE];
    const int t = threadIdx.x;
    const int i = blockIdx.x * SCAN_TILE + t;
    s[t] = (i < N_NODES) ? cnt[i] : 0;
    __syncthreads();
    for (int off = 1; off < SCAN_TILE; off <<= 1) {
        int x = (t >= off) ? s[t - off] : 0;
        __syncthreads();
        s[t] += x;
        __syncthreads();
    }
    if (i < N_NODES) tileinc[i] = s[t];
    if (t == SCAN_TILE - 1) bsum[blockIdx.x] = s[t];
}

// Pass 2: one block scans the 391 tile totals (inclusive, in place).
__global__ __launch_bounds__(512) void scan_p2_kernel(int* __restrict__ bsum)
{
    __shared__ int s[512];
    const int t = threadIdx.x;
    s[t] = (t < NTILES) ? bsum[t] : 0;
    __syncthreads();
    for (int off = 1; off < 512; off <<= 1) {
        int x = (t >= off) ? s[t - off] : 0;
        __syncthreads();
        s[t] += x;
        __syncthreads();
    }
    if (t < NTILES) bsum[t] = s[t];
}

// Pass 3: exclusive row_ptr + cursor init.
__global__ __launch_bounds__(256) void scan_p3_kernel(
    const int* __restrict__ cnt, const int* __restrict__ tileinc,
    const int* __restrict__ bsum, int* __restrict__ row_ptr, int* __restrict__ cursor)
{
    const int i = blockIdx.x * 256 + threadIdx.x;
    if (i >= N_NODES) return;
    const int b = i >> 8;   // i / 256
    const int excl = tileinc[i] - cnt[i] + (b > 0 ? bsum[b - 1] : 0);
    row_ptr[i] = excl;
    cursor[i]  = excl;
    if (i == 0) row_ptr[N_NODES] = N_EDGES;
}

// Scatter edges into CSR order; fuse the dw1 lookup into a per-edge weight.
__global__ __launch_bounds__(256) void sort_scatter_kernel(
    const int* __restrict__ erow, const int* __restrict__ ecol,
    const int* __restrict__ etime, const float* __restrict__ dw1,
    int* __restrict__ cursor, int* __restrict__ scol, float* __restrict__ sw)
{
    const int e = blockIdx.x * 256 + threadIdx.x;
    if (e >= N_EDGES) return;
    const int row = erow[e];
    const int pos = atomicAdd(&cursor[row], 1);
    scol[pos] = ecol[e];
    sw[pos]   = dw1[etime[e]];
}

// ---------------------------------------------------------------------------
// Atomic-free reduce: 32 lanes per row; lane c owns output column c.
// Fuses the dw2 window scale. Writes every output element exactly once.
// ---------------------------------------------------------------------------
__global__ __launch_bounds__(256) void reduce_scale_kernel(
    const float* __restrict__ h, const int* __restrict__ row_ptr,
    const int* __restrict__ scol, const float* __restrict__ sw,
    const float* __restrict__ dw2, const int* __restrict__ arrive,
    const int* __restrict__ obs, float* __restrict__ out)
{
    const int r = blockIdx.x * 8 + (threadIdx.x >> 5);   // 12500*8 = 100000 exact
    const int c = threadIdx.x & 31;

    const int beg = row_ptr[r];
    const int end = row_ptr[r + 1];

    float acc = 0.f;
    int k = beg;
    for (; k + 2 <= end; k += 2) {
        const float w0 = sw[k];
        const float w1 = sw[k + 1];
        const int   c0 = scol[k];
        const int   c1 = scol[k + 1];
        const float v0 = h[(size_t)c0 * D_OUT + c];
        const float v1 = h[(size_t)c1 * D_OUT + c];
        acc = fmaf(w0, v0, acc);
        acc = fmaf(w1, v1, acc);
    }
    if (k < end) acc = fmaf(sw[k], h[(size_t)scol[k] * D_OUT + c], acc);

    const float s = dw2[60 * obs[0] - arrive[r] - 1];
    out[(size_t)r * D_OUT + c] = acc * s;
}

extern "C" void kernel_launch(void* const* d_in, const int* in_sizes, int n_in,
                              void* d_out, int out_size, void* d_ws, size_t ws_size,
                              hipStream_t stream)
{
    const float* input  = (const float*)d_in[0];   // [N, 128]
    const float* W      = (const float*)d_in[1];   // [128, 32]
    const float* dw1    = (const float*)d_in[2];   // [3600]
    const float* dw2    = (const float*)d_in[3];   // [3600]
    const int*   erow   = (const int*)d_in[4];     // [E]
    const int*   ecol   = (const int*)d_in[5];     // [E]
    const int*   etime  = (const int*)d_in[6];     // [E]
    const int*   arrive = (const int*)d_in[7];     // [N]
    const int*   obs    = (const int*)d_in[8];     // scalar

    float* out = (float*)d_out;                    // [N, 32]

    // Workspace layout (all 4-byte elements; total ~26.8 MB)
    float* h       = (float*)d_ws;                         // N*32
    int*   cnt     = (int*)(h + (size_t)N_NODES * D_OUT);  // N
    int*   tileinc = cnt + N_NODES;                        // N
    int*   row_ptr = tileinc + N_NODES;                    // N+1
    int*   cursor  = row_ptr + N_NODES + 1;                // N
    int*   bsum    = cursor + N_NODES;                     // 512
    int*   scol    = bsum + 512;                           // E
    float* sw      = (float*)(scol + N_EDGES);             // E

    // Zero only the histogram bins (ws is poisoned to 0xAA each launch).
    hipMemsetAsync(cnt, 0, (size_t)N_NODES * sizeof(int), stream);

    gemm_relu_kernel<<<N_NODES / 8, 256, 0, stream>>>(input, W, h);

    hist_kernel<<<(N_EDGES + 255) / 256, 256, 0, stream>>>(erow, cnt);
    scan_p1_kernel<<<NTILES, SCAN_TILE, 0, stream>>>(cnt, tileinc, bsum);
    scan_p2_kernel<<<1, 512, 0, stream>>>(bsum);
    scan_p3_kernel<<<(N_NODES + 255) / 256, 256, 0, stream>>>(
        cnt, tileinc, bsum, row_ptr, cursor);
    sort_scatter_kernel<<<(N_EDGES + 255) / 256, 256, 0, stream>>>(
        erow, ecol, etime, dw1, cursor, scol, sw);

    reduce_scale_kernel<<<N_NODES / 8, 256, 0, stream>>>(
        h, row_ptr, scol, sw, dw2, arrive, obs, out);
}